// Round 28
// baseline (105.941 us; speedup 1.0000x reference)
//
#include <hip/hip_runtime.h>
#include <math.h>

constexpr int cB  = 16;
constexpr int cN  = 64;
constexpr int EMB = 32;
constexpr int NL  = 3;
constexpr int CDIM = 24;
constexpr int LOD = NL * CDIM;      // 72
constexpr int NB  = 10;
constexpr int H   = 150;
constexpr int CR  = 219;
constexpr int C2  = 438;
constexpr int HD  = 128;
constexpr int NSP = 6;              // species count
constexpr int GC  = NSP * LOD;      // 432 G-columns
constexpr int GCP = 512;            // padded W2 row
constexpr int TBL = 512;            // r-table resolution (measured absmax 0.0)
constexpr float RADIUS = 2.0f;

__device__ __forceinline__ float sp5(float x) {
    return fmaxf(x, 0.0f) + 0.2f * log1pf(expf(-5.0f * fabsf(x)));
}
__device__ __forceinline__ float sp1(float x) {
    return fmaxf(x, 0.0f) + log1pf(expf(-fabsf(x)));
}

// Merged prologue kernel.
// blocks 0..89: W2 build + Pbz; blocks 90..153: warm-touch res_W;
// blocks 154..161: zero pooled2 + counter.
__global__ void __launch_bounds__(256) k_prep(const float* __restrict__ emb_W,
                                              const float* __restrict__ rW3,
                                              const float* __restrict__ rb3,
                                              const float* __restrict__ res_W,
                                              float* __restrict__ W2,
                                              float* __restrict__ Pbz,
                                              float* __restrict__ pooled2,
                                              float* __restrict__ touch) {
    int bx = blockIdx.x;
    int t = threadIdx.x;
    __shared__ float e[EMB];
    if (bx < 90) {
        int z = bx / 15, hb = bx - (bx / 15) * 15;   // 6 x 15, 10 k-rows each
        if (t < EMB) e[t] = emb_W[z * EMB + t];
        __syncthreads();
        for (int o = t; o < 10 * LOD; o += 256) {
            int k = hb * 10 + o / LOD, lo = o % LOD;
            const float* wr = &rW3[(size_t)k * (LOD * EMB) + lo * EMB];
            float s = 0.0f;
            #pragma unroll
            for (int i = 0; i < EMB; ++i) s = fmaf(wr[i], e[i], s);
            W2[(size_t)k * GCP + z * LOD + lo] = s;
        }
        if (z == 0) {  // zero the pad cols 432..511
            for (int o = t; o < 10 * (GCP - GC); o += 256) {
                int k = hb * 10 + o / (GCP - GC), c = GC + o % (GCP - GC);
                W2[(size_t)k * GCP + c] = 0.0f;
            }
        }
        if (hb == 0 && t < LOD) {
            float s = 0.0f;
            #pragma unroll
            for (int i = 0; i < EMB; ++i) s = fmaf(rb3[t * EMB + i], e[i], s);
            Pbz[z * LOD + t] = s;
        }
    } else if (bx < 154) {
        // warm-touch res_W: 64 blocks x 256 thr, float4-coalesced; live dummy write
        int wb = bx - 90;
        const int n4 = (CR * CR) / 4;                // 11990 float4s
        float s = 0.0f;
        for (int i = wb * 256 + t; i < n4; i += 64 * 256) {
            float4 v = *(const float4*)&res_W[4 * i];
            s += v.x + v.y + v.z + v.w;
        }
        touch[wb * 256 + t] = s;                     // deterministic, keeps loads live
    } else {
        // zero pooled2 (cB*C2) + counter (1)
        int pb = bx - 154;                           // 8 blocks
        int total = cB * C2 + 1;                     // 7009
        for (int i = pb * 256 + t; i < total; i += 8 * 256)
            pooled2[i] = 0.0f;
    }
}

// Fused table chain: 1 row/block x 512 blocks (2/CU), weights streamed from L1/L2.
__global__ void __launch_bounds__(256) k_chain(const float* __restrict__ rW0,
                                               const float* __restrict__ rb0,
                                               const float* __restrict__ rW1,
                                               const float* __restrict__ rb1,
                                               const float* __restrict__ rW2,
                                               const float* __restrict__ rb2,
                                               const float* __restrict__ W2,
                                               const float* __restrict__ Pbz,
                                               float* __restrict__ G) {
    const int row = blockIdx.x;
    const int t = threadIdx.x;

    __shared__ __align__(16) float bas[10];
    __shared__ __align__(16) float hA[152];
    __shared__ __align__(16) float hB[152];

    if (t == 0) {
        float r = (float)row * (RADIUS / (float)(TBL - 1));
        #pragma unroll
        for (int k = 0; k < NB; ++k) {
            float d = r * 4.5f - (float)k;
            float v = 0.0f;
            if (fabsf(d) < 1.0f) { float cc = cosf(1.57079632679489662f * d); v = cc * cc; }
            bas[k] = v;
        }
    }
    __syncthreads();

    // ---- L0: K=10 ----
    if (t < H) {
        float a0 = 0;
        #pragma unroll
        for (int k = 0; k < NB; ++k)
            a0 = fmaf(bas[k], rW0[k * H + t], a0);
        hA[t] = sp5(a0 + rb0[t]);
    }
    __syncthreads();

    // ---- L1 (hA->hB), L2 (hB->hA): K=150 ----
    for (int layer = 0; layer < 2; ++layer) {
        const float* W   = layer ? rW2 : rW1;
        const float* bb  = layer ? rb2 : rb1;
        const float* src = layer ? hB : hA;
        float*       dst = layer ? hA : hB;
        float a0 = 0;
        if (t < H) {
            #pragma unroll 10
            for (int k = 0; k < H; ++k)
                a0 = fmaf(src[k], W[k * H + t], a0);
        }
        __syncthreads();   // src reads done before dst overwrite (hA<->hB alternate, safe)
        if (t < H) dst[t] = sp5(a0 + bb[t]);
        __syncthreads();
    }

    // ---- G: out[row][c] = sum_k hA[k]*W2[k][c] + Pbz[c], c = 4t..4t+4 ----
    if (t < 108) {
        const int g0 = 4 * t;
        float4 c0 = {0, 0, 0, 0};
        #pragma unroll 10
        for (int k = 0; k < H; ++k) {
            float x = hA[k];
            float4 w = *(const float4*)&W2[(size_t)k * GCP + g0];
            c0.x = fmaf(x, w.x, c0.x); c0.y = fmaf(x, w.y, c0.y);
            c0.z = fmaf(x, w.z, c0.z); c0.w = fmaf(x, w.w, c0.w);
        }
        float4 p = *(const float4*)&Pbz[g0];
        float4 o;
        o.x = c0.x + p.x; o.y = c0.y + p.y; o.z = c0.z + p.z; o.w = c0.w + p.w;
        *(float4*)&G[(size_t)row * GC + g0] = o;
    }
}

// Fully fused per (b,a): ballot-compacted gather + Y-reduce -> xr; in-block residual
// GEMM; xv^2/o^2 atomics into pooled2; the LAST block runs the whole head inline.
__global__ void __launch_bounds__(256) k_red(const float* __restrict__ xyz,
                                             const int* __restrict__ Z,
                                             const float* __restrict__ body23,
                                             const float* __restrict__ G,
                                             const float* __restrict__ res_W,
                                             const float* __restrict__ res_b,
                                             const float* __restrict__ c_W,
                                             const float* __restrict__ c_b,
                                             const float* __restrict__ bn_g,
                                             const float* __restrict__ bn_b,
                                             const float* __restrict__ o_W,
                                             const float* __restrict__ o_b,
                                             float* __restrict__ pooled2,
                                             float* __restrict__ out) {
    __shared__ __align__(16) float SH[9056];     // union scratch (36.2 KB)
    float* ym    = SH;                           // [64][12] = 768
    float* ymc   = SH + 768;                     // [64][12] = 768
    float* ps    = SH + 1536;                    // [64][76] = 4864 (16B-aligned)
    float* xr    = SH + 6400;                    // [224]
    int*   t0s   = (int*)(SH + 6624);            // [64]
    float* wls   = SH + 6688;                    // [64]
    int*   zs    = (int*)(SH + 6752);            // [64]
    int*   alist = (int*)(SH + 6816);            // [64]
    int*   cnt_p = (int*)(SH + 6880);            // [1]
    __shared__ int is_last_s;

    int ba = blockIdx.x;
    int b = ba >> 6, a = ba & 63;
    int t = threadIdx.x;
    if (t < 64) {
        int n = t;
        float ax = xyz[((size_t)b * cN + a) * 3 + 0];
        float ay = xyz[((size_t)b * cN + a) * 3 + 1];
        float az = xyz[((size_t)b * cN + a) * 3 + 2];
        float d0 = ax - xyz[((size_t)b * cN + n) * 3 + 0];
        float d1 = ay - xyz[((size_t)b * cN + n) * 3 + 1];
        float d2 = az - xyz[((size_t)b * cN + n) * 3 + 2];
        float s = d0 * d0 + d1 * d1 + d2 * d2;
        float r = sqrtf(s + 1e-12f);
        bool m = (r < RADIUS) && (r > 1e-6f);
        float u = r * ((float)(TBL - 1) / RADIUS);
        int t0 = (int)u;
        if (t0 > TBL - 2) t0 = TBL - 2;
        t0s[n] = t0;
        wls[n] = u - (float)t0;
        zs[n] = Z[b * cN + n];
        float inv = 1.0f / r;
        float x = d0 * inv, y = d1 * inv, z = d2 * inv;
        ym[n * 12 + 0] = 0.28209479177387814f;
        ym[n * 12 + 1] = 0.4886025119029199f * y;
        ym[n * 12 + 2] = 0.4886025119029199f * z;
        ym[n * 12 + 3] = 0.4886025119029199f * x;
        ym[n * 12 + 4] = 1.0925484305920792f * x * y;
        ym[n * 12 + 5] = 1.0925484305920792f * y * z;
        ym[n * 12 + 6] = 0.31539156525252005f * (3.0f * z * z - 1.0f);
        ym[n * 12 + 7] = 1.0925484305920792f * x * z;
        ym[n * 12 + 8] = 0.5462742152960396f * (x * x - y * y);
        // ballot compaction (wave 0 only; t==lane)
        unsigned long long mask = __ballot(m);
        int rank = __popcll(mask & ((1ull << n) - 1ull));
        if (m) alist[rank] = n;
        if (n == 0) cnt_p[0] = (int)__popcll(mask);
    }
    __syncthreads();
    int cnt = cnt_p[0];
    for (int i = t; i < cnt * 9; i += 256) {
        int ci = i / 9, yi = i - ci * 9;
        ymc[ci * 12 + yi] = ym[alist[ci] * 12 + yi];
    }
    for (int i = t; i < cnt * 18; i += 256) {
        int ci = i / 18, q = i - ci * 18;
        int n = alist[ci];
        const float* g = &G[(size_t)t0s[n] * GC + zs[n] * LOD + 4 * q];
        float4 g0 = *(const float4*)g;
        float4 g1 = *(const float4*)(g + GC);
        float wl = wls[n];
        float4 v;
        v.x = g0.x + wl * (g1.x - g0.x);
        v.y = g0.y + wl * (g1.y - g0.y);
        v.z = g0.z + wl * (g1.z - g0.z);
        v.w = g0.w + wl * (g1.w - g0.w);
        *(float4*)&ps[ci * 76 + 4 * q] = v;
    }
    __syncthreads();
    if (t < 216) {
        int lo, yi;
        if (t < 24) { lo = t; yi = 0; }
        else if (t < 96) { int q = t - 24; int o = q / 3; lo = 24 + o; yi = 1 + (q - o * 3); }
        else { int q = t - 96; int o = q / 5; lo = 48 + o; yi = 4 + (q - o * 5); }
        float acc = 0.0f;
        #pragma unroll 4
        for (int ci = 0; ci < cnt; ++ci)
            acc = fmaf(ps[ci * 76 + lo], ymc[ci * 12 + yi], acc);
        xr[3 + t] = acc * 0.125f;
    } else if (t < 219) {
        xr[t - 216] = body23[(size_t)ba * 3 + (t - 216)];
    }
    __syncthreads();
    if (t < CR) {
        float xv = xr[t];
        float s = 0.0f;
        #pragma unroll 8
        for (int k = 0; k < CR; ++k)
            s = fmaf(xr[k], res_W[(size_t)k * CR + t], s);
        float o = xv + sp5(res_b[t] + s);
        atomicAdd(&pooled2[b * C2 + t],      xv * xv);
        atomicAdd(&pooled2[b * C2 + CR + t], o * o);
    }
    __syncthreads();                                  // drain atomics (vmcnt0 at barrier)
    if (t == 0) {
        __threadfence();
        unsigned int old = atomicAdd((unsigned int*)&pooled2[cB * C2], 1u);
        is_last_s = (old == (unsigned int)(cB * cN - 1));
    }
    __syncthreads();
    if (!is_last_s) return;

    // ================= inline head (last block only) =================
    float* sqq   = SH;                                // [cB*C2] = 7008
    float* part2 = SH + 7008;                         // [HD*16] = 2048
    for (int i = t; i < cB * C2; i += 256)
        sqq[i] = sqrtf(pooled2[i]);                   // L2-fresh (never L1-cached here)
    __syncthreads();
    if (t < HD) {
        int j = t;
        float acc[cB];
        #pragma unroll
        for (int bb = 0; bb < cB; ++bb) acc[bb] = 0.0f;
        for (int ch = 0; ch < C2; ++ch) {
            float wv = c_W[ch * HD + j];              // coalesced across j
            #pragma unroll
            for (int bb = 0; bb < cB; ++bb)
                acc[bb] = fmaf(sqq[bb * C2 + ch], wv, acc[bb]);
        }
        float cb = c_b[j];
        float h[cB];
        float mu = 0.0f;
        #pragma unroll
        for (int bb = 0; bb < cB; ++bb) { h[bb] = sp1(acc[bb] + cb); mu += h[bb]; }
        mu *= (1.0f / cB);
        float var = 0.0f;
        #pragma unroll
        for (int bb = 0; bb < cB; ++bb) { float d = h[bb] - mu; var = fmaf(d, d, var); }
        var *= (1.0f / cB);
        float sc = bn_g[j] / sqrtf(var + 1e-5f);
        float bnb = bn_b[j];
        float ow = o_W[j];
        #pragma unroll
        for (int bb = 0; bb < cB; ++bb)
            part2[j * cB + bb] = sp1((h[bb] - mu) * sc + bnb) * ow;
    }
    __syncthreads();
    if (t < cB) {
        float s = 0.0f;
        #pragma unroll 8
        for (int j = 0; j < HD; ++j) s += part2[j * cB + t];
        out[t] = 1.0f / (1.0f + expf(-(s + o_b[0])));
    }
}

extern "C" void kernel_launch(void* const* d_in, const int* in_sizes, int n_in,
                              void* d_out, int out_size, void* d_ws, size_t ws_size,
                              hipStream_t stream) {
    const float* xyz    = (const float*)d_in[0];
    const int*   Z      = (const int*)d_in[1];
    const float* body23 = (const float*)d_in[2];
    const float* emb_W  = (const float*)d_in[3];
    const float* rW0    = (const float*)d_in[4];
    const float* rb0    = (const float*)d_in[5];
    const float* rW1    = (const float*)d_in[6];
    const float* rb1    = (const float*)d_in[7];
    const float* rW2    = (const float*)d_in[8];
    const float* rb2    = (const float*)d_in[9];
    const float* rW3    = (const float*)d_in[10];
    const float* rb3    = (const float*)d_in[11];
    const float* res_W  = (const float*)d_in[12];
    const float* res_b  = (const float*)d_in[13];
    const float* c_W    = (const float*)d_in[14];
    const float* c_b    = (const float*)d_in[15];
    const float* bn_g   = (const float*)d_in[16];
    const float* bn_b   = (const float*)d_in[17];
    const float* o_W    = (const float*)d_in[18];
    const float* o_b    = (const float*)d_in[19];

    float* w       = (float*)d_ws;
    float* W2      = w;                       // 150*512    = 76800
    float* Pbz     = W2 + 76800;              // 432
    float* G       = Pbz + 432;               // 512*432    = 221184
    float* pooled2 = G + 221184;              // 16*438 + 1 counter = 7009 (pad 7040)
    float* touch   = pooled2 + 7040;          // 64*256     = 16384
    (void)in_sizes; (void)n_in; (void)out_size; (void)ws_size;

    k_prep <<<162, 256, 0, stream>>>(emb_W, rW3, rb3, res_W, W2, Pbz, pooled2, touch);
    k_chain<<<TBL, 256, 0, stream>>>(rW0, rb0, rW1, rb1, rW2, rb2, W2, Pbz, G);
    k_red  <<<cB * cN, 256, 0, stream>>>(xyz, Z, body23, G, res_W, res_b,
                                         c_W, c_b, bn_g, bn_b, o_W, o_b,
                                         pooled2, (float*)d_out);
}

// Round 29
// 59.460 us; speedup vs baseline: 1.7817x; 1.7817x over previous
//
#include <hip/hip_runtime.h>
#include <math.h>

constexpr int cB  = 16;
constexpr int cN  = 64;
constexpr int EMB = 32;
constexpr int NL  = 3;
constexpr int CDIM = 24;
constexpr int LOD = NL * CDIM;      // 72
constexpr int NB  = 10;
constexpr int H   = 150;
constexpr int CR  = 219;
constexpr int C2  = 438;
constexpr int HD  = 128;
constexpr int NSP = 6;              // species count
constexpr int GC  = NSP * LOD;      // 432 G-columns
constexpr int GCP = 512;            // padded W2 row
constexpr int TBL = 512;            // r-table resolution (measured absmax 0.0)
constexpr float RADIUS = 2.0f;

__device__ __forceinline__ float sp5(float x) {
    return fmaxf(x, 0.0f) + 0.2f * log1pf(expf(-5.0f * fabsf(x)));
}
__device__ __forceinline__ float sp1(float x) {
    return fmaxf(x, 0.0f) + log1pf(expf(-fabsf(x)));
}

// Merged prologue kernel.
// blocks 0..89: W2 build + Pbz; blocks 90..153: warm-touch res_W;
// blocks 154..185: c_Wt transpose (warms c_W) + zero pooled2/partial/counter.
__global__ void __launch_bounds__(256) k_prep(const float* __restrict__ emb_W,
                                              const float* __restrict__ rW3,
                                              const float* __restrict__ rb3,
                                              const float* __restrict__ c_W,
                                              const float* __restrict__ res_W,
                                              float* __restrict__ W2,
                                              float* __restrict__ Pbz,
                                              float* __restrict__ c_Wt,
                                              float* __restrict__ pooled2,
                                              float* __restrict__ partial,
                                              float* __restrict__ touch) {
    int bx = blockIdx.x;
    int t = threadIdx.x;
    __shared__ float e[EMB];
    if (bx < 90) {
        int z = bx / 15, hb = bx - (bx / 15) * 15;   // 6 x 15, 10 k-rows each
        if (t < EMB) e[t] = emb_W[z * EMB + t];
        __syncthreads();
        for (int o = t; o < 10 * LOD; o += 256) {
            int k = hb * 10 + o / LOD, lo = o % LOD;
            const float* wr = &rW3[(size_t)k * (LOD * EMB) + lo * EMB];
            float s = 0.0f;
            #pragma unroll
            for (int i = 0; i < EMB; ++i) s = fmaf(wr[i], e[i], s);
            W2[(size_t)k * GCP + z * LOD + lo] = s;
        }
        if (z == 0) {  // zero the pad cols 432..511
            for (int o = t; o < 10 * (GCP - GC); o += 256) {
                int k = hb * 10 + o / (GCP - GC), c = GC + o % (GCP - GC);
                W2[(size_t)k * GCP + c] = 0.0f;
            }
        }
        if (hb == 0 && t < LOD) {
            float s = 0.0f;
            #pragma unroll
            for (int i = 0; i < EMB; ++i) s = fmaf(rb3[t * EMB + i], e[i], s);
            Pbz[z * LOD + t] = s;
        }
    } else if (bx < 154) {
        // warm-touch res_W: 64 blocks x 256 thr, float4-coalesced; live dummy write
        int wb = bx - 90;
        const int n4 = (CR * CR) / 4;                // 11990 float4s
        float s = 0.0f;
        for (int i = wb * 256 + t; i < n4; i += 64 * 256) {
            float4 v = *(const float4*)&res_W[4 * i];
            s += v.x + v.y + v.z + v.w;
        }
        touch[wb * 256 + t] = s;                     // deterministic, keeps loads live
    } else {
        // misc: c_Wt transpose (HD*440) + pooled2 (cB*C2) + partial (HD*16+1 counter)
        int pb = bx - 154;                           // 32 blocks
        int totalT = HD * 440;                       // 56320
        int total2 = totalT + cB * C2 + HD * 16 + 1; // +7008+2049 = 65377
        for (int i = pb * 256 + t; i < total2; i += 32 * 256) {
            if (i < totalT) {
                int jj = i / 440, ch = i - jj * 440;
                c_Wt[i] = (ch < C2) ? c_W[ch * HD + jj] : 0.0f;
            } else if (i < totalT + cB * C2) {
                pooled2[i - totalT] = 0.0f;
            } else {
                partial[i - totalT - cB * C2] = 0.0f;  // partials + counter
            }
        }
    }
}

// Fused table chain: 1 row/block x 512 blocks (2/CU), weights streamed from L1/L2.
__global__ void __launch_bounds__(256) k_chain(const float* __restrict__ rW0,
                                               const float* __restrict__ rb0,
                                               const float* __restrict__ rW1,
                                               const float* __restrict__ rb1,
                                               const float* __restrict__ rW2,
                                               const float* __restrict__ rb2,
                                               const float* __restrict__ W2,
                                               const float* __restrict__ Pbz,
                                               float* __restrict__ G) {
    const int row = blockIdx.x;
    const int t = threadIdx.x;

    __shared__ __align__(16) float bas[10];
    __shared__ __align__(16) float hA[152];
    __shared__ __align__(16) float hB[152];

    if (t == 0) {
        float r = (float)row * (RADIUS / (float)(TBL - 1));
        #pragma unroll
        for (int k = 0; k < NB; ++k) {
            float d = r * 4.5f - (float)k;
            float v = 0.0f;
            if (fabsf(d) < 1.0f) { float cc = cosf(1.57079632679489662f * d); v = cc * cc; }
            bas[k] = v;
        }
    }
    __syncthreads();

    // ---- L0: K=10 ----
    if (t < H) {
        float a0 = 0;
        #pragma unroll
        for (int k = 0; k < NB; ++k)
            a0 = fmaf(bas[k], rW0[k * H + t], a0);
        hA[t] = sp5(a0 + rb0[t]);
    }
    __syncthreads();

    // ---- L1 (hA->hB), L2 (hB->hA): K=150 ----
    for (int layer = 0; layer < 2; ++layer) {
        const float* W   = layer ? rW2 : rW1;
        const float* bb  = layer ? rb2 : rb1;
        const float* src = layer ? hB : hA;
        float*       dst = layer ? hA : hB;
        float a0 = 0;
        if (t < H) {
            #pragma unroll 10
            for (int k = 0; k < H; ++k)
                a0 = fmaf(src[k], W[k * H + t], a0);
        }
        __syncthreads();
        if (t < H) dst[t] = sp5(a0 + bb[t]);
        __syncthreads();
    }

    // ---- G: out[row][c] = sum_k hA[k]*W2[k][c] + Pbz[c], c = 4t..4t+4 ----
    if (t < 108) {
        const int g0 = 4 * t;
        float4 c0 = {0, 0, 0, 0};
        #pragma unroll 10
        for (int k = 0; k < H; ++k) {
            float x = hA[k];
            float4 w = *(const float4*)&W2[(size_t)k * GCP + g0];
            c0.x = fmaf(x, w.x, c0.x); c0.y = fmaf(x, w.y, c0.y);
            c0.z = fmaf(x, w.z, c0.z); c0.w = fmaf(x, w.w, c0.w);
        }
        float4 p = *(const float4*)&Pbz[g0];
        float4 o;
        o.x = c0.x + p.x; o.y = c0.y + p.y; o.z = c0.z + p.z; o.w = c0.w + p.w;
        *(float4*)&G[(size_t)row * GC + g0] = o;
    }
}

// Fully fused per (b,a): ballot-compacted gather + Y-reduce -> xr; in-block residual
// GEMM vs L2-warm res_W; xv^2 and o^2 atomically accumulated into pooled2.
__global__ void __launch_bounds__(256) k_red(const float* __restrict__ xyz,
                                             const int* __restrict__ Z,
                                             const float* __restrict__ body23,
                                             const float* __restrict__ G,
                                             const float* __restrict__ res_W,
                                             const float* __restrict__ res_b,
                                             float* __restrict__ pooled2) {
    int ba = blockIdx.x;
    int b = ba >> 6, a = ba & 63;
    int t = threadIdx.x;
    __shared__ float ym[64][12];
    __shared__ float ymc[64][12];
    __shared__ __align__(16) float ps[64][76];
    __shared__ float xr[224];
    __shared__ int t0s[64];
    __shared__ float wls[64];
    __shared__ int zs[64];
    __shared__ int alist[64];
    __shared__ int cnt_s;
    if (t < 64) {
        int n = t;
        float ax = xyz[((size_t)b * cN + a) * 3 + 0];
        float ay = xyz[((size_t)b * cN + a) * 3 + 1];
        float az = xyz[((size_t)b * cN + a) * 3 + 2];
        float d0 = ax - xyz[((size_t)b * cN + n) * 3 + 0];
        float d1 = ay - xyz[((size_t)b * cN + n) * 3 + 1];
        float d2 = az - xyz[((size_t)b * cN + n) * 3 + 2];
        float s = d0 * d0 + d1 * d1 + d2 * d2;
        float r = sqrtf(s + 1e-12f);
        bool m = (r < RADIUS) && (r > 1e-6f);
        float u = r * ((float)(TBL - 1) / RADIUS);
        int t0 = (int)u;
        if (t0 > TBL - 2) t0 = TBL - 2;
        t0s[n] = t0;
        wls[n] = u - (float)t0;
        zs[n] = Z[b * cN + n];
        float inv = 1.0f / r;
        float x = d0 * inv, y = d1 * inv, z = d2 * inv;
        ym[n][0] = 0.28209479177387814f;
        ym[n][1] = 0.4886025119029199f * y;
        ym[n][2] = 0.4886025119029199f * z;
        ym[n][3] = 0.4886025119029199f * x;
        ym[n][4] = 1.0925484305920792f * x * y;
        ym[n][5] = 1.0925484305920792f * y * z;
        ym[n][6] = 0.31539156525252005f * (3.0f * z * z - 1.0f);
        ym[n][7] = 1.0925484305920792f * x * z;
        ym[n][8] = 0.5462742152960396f * (x * x - y * y);
        // ballot compaction (wave 0 only; t==lane)
        unsigned long long mask = __ballot(m);
        int rank = __popcll(mask & ((1ull << n) - 1ull));
        if (m) alist[rank] = n;
        if (n == 0) cnt_s = (int)__popcll(mask);
    }
    __syncthreads();
    int cnt = cnt_s;
    // compact ym rows
    for (int i = t; i < cnt * 9; i += 256) {
        int ci = i / 9, yi = i - ci * 9;
        ymc[ci][yi] = ym[alist[ci]][yi];
    }
    // compacted float4 gather+lerp: 18 float4 groups per active neighbor
    for (int i = t; i < cnt * 18; i += 256) {
        int ci = i / 18, q = i - ci * 18;
        int n = alist[ci];
        const float* g = &G[(size_t)t0s[n] * GC + zs[n] * LOD + 4 * q];
        float4 g0 = *(const float4*)g;
        float4 g1 = *(const float4*)(g + GC);
        float wl = wls[n];
        float4 v;
        v.x = g0.x + wl * (g1.x - g0.x);
        v.y = g0.y + wl * (g1.y - g0.y);
        v.z = g0.z + wl * (g1.z - g0.z);
        v.w = g0.w + wl * (g1.w - g0.w);
        *(float4*)&ps[ci][4 * q] = v;
    }
    __syncthreads();
    if (t < 216) {
        int lo, yi;
        if (t < 24) { lo = t; yi = 0; }
        else if (t < 96) { int q = t - 24; int o = q / 3; lo = 24 + o; yi = 1 + (q - o * 3); }
        else { int q = t - 96; int o = q / 5; lo = 48 + o; yi = 4 + (q - o * 5); }
        float acc = 0.0f;
        #pragma unroll 4
        for (int ci = 0; ci < cnt; ++ci)
            acc = fmaf(ps[ci][lo], ymc[ci][yi], acc);
        xr[3 + t] = acc * 0.125f;
    } else if (t < 219) {
        xr[t - 216] = body23[(size_t)ba * 3 + (t - 216)];
    }
    __syncthreads();
    // in-block residual: s[t] = sum_k xr[k] * res_W[k][t]  (coalesced, L2-warm)
    if (t < CR) {
        float xv = xr[t];
        float s = 0.0f;
        #pragma unroll 8
        for (int k = 0; k < CR; ++k)
            s = fmaf(xr[k], res_W[(size_t)k * CR + t], s);
        float o = xv + sp5(res_b[t] + s);
        atomicAdd(&pooled2[b * C2 + t],      xv * xv);
        atomicAdd(&pooled2[b * C2 + CR + t], o * o);
    }
}

// Merged head, contention-free: block j computes hh[b][j], BN over b, softplus,
// writes its own partial row partial[j][16]; last block reduces 128x16 + sigmoid.
__global__ void __launch_bounds__(64) k_headm(const float* __restrict__ pooled2,
                                              const float* __restrict__ c_Wt,
                                              const float* __restrict__ c_b,
                                              const float* __restrict__ bn_g,
                                              const float* __restrict__ bn_b,
                                              const float* __restrict__ o_W,
                                              const float* __restrict__ o_b,
                                              float* __restrict__ partial,
                                              float* __restrict__ out) {
    int j = blockIdx.x;
    int l = threadIdx.x;
    float acc[cB];
    #pragma unroll
    for (int b = 0; b < cB; ++b) acc[b] = 0.0f;
    const float* wr = &c_Wt[j * 440];
    for (int ch = l; ch < C2; ch += 64) {
        float wv = wr[ch];
        #pragma unroll
        for (int b = 0; b < cB; ++b)
            acc[b] = fmaf(sqrtf(pooled2[b * C2 + ch]), wv, acc[b]);
    }
    #pragma unroll
    for (int off = 32; off >= 1; off >>= 1) {
        #pragma unroll
        for (int b = 0; b < cB; ++b) acc[b] += __shfl_xor(acc[b], off, 64);
    }
    __shared__ int is_last;
    if (l == 0) {
        float cb = c_b[j];
        float h[cB];
        float mu = 0.0f;
        #pragma unroll
        for (int b = 0; b < cB; ++b) { h[b] = sp1(acc[b] + cb); mu += h[b]; }
        mu *= (1.0f / cB);
        float var = 0.0f;
        #pragma unroll
        for (int b = 0; b < cB; ++b) { float d = h[b] - mu; var = fmaf(d, d, var); }
        var *= (1.0f / cB);
        float sc = bn_g[j] / sqrtf(var + 1e-5f);
        float bnb = bn_b[j];
        float ow = o_W[j];
        #pragma unroll
        for (int b = 0; b < cB; ++b)
            partial[j * cB + b] = sp1((h[b] - mu) * sc + bnb) * ow;   // own row, no atomics
        __threadfence();
        unsigned int old = atomicAdd((unsigned int*)&partial[HD * cB], 1u);
        is_last = (old == (unsigned int)(HD - 1));
    }
    __syncthreads();
    if (is_last) {
        // reduce partial[128][16]: lane l sums 32 rows for column (l&15), group l>>4
        int bcol = l & 15, grp = l >> 4;
        float s = 0.0f;
        #pragma unroll 8
        for (int jr = grp * 32; jr < grp * 32 + 32; ++jr)
            s += partial[jr * cB + bcol];
        s += __shfl_down(s, 32, 64);
        s += __shfl_down(s, 16, 64);
        if (l < cB)
            out[l] = 1.0f / (1.0f + expf(-(s + o_b[0])));
    }
}

extern "C" void kernel_launch(void* const* d_in, const int* in_sizes, int n_in,
                              void* d_out, int out_size, void* d_ws, size_t ws_size,
                              hipStream_t stream) {
    const float* xyz    = (const float*)d_in[0];
    const int*   Z      = (const int*)d_in[1];
    const float* body23 = (const float*)d_in[2];
    const float* emb_W  = (const float*)d_in[3];
    const float* rW0    = (const float*)d_in[4];
    const float* rb0    = (const float*)d_in[5];
    const float* rW1    = (const float*)d_in[6];
    const float* rb1    = (const float*)d_in[7];
    const float* rW2    = (const float*)d_in[8];
    const float* rb2    = (const float*)d_in[9];
    const float* rW3    = (const float*)d_in[10];
    const float* rb3    = (const float*)d_in[11];
    const float* res_W  = (const float*)d_in[12];
    const float* res_b  = (const float*)d_in[13];
    const float* c_W    = (const float*)d_in[14];
    const float* c_b    = (const float*)d_in[15];
    const float* bn_g   = (const float*)d_in[16];
    const float* bn_b   = (const float*)d_in[17];
    const float* o_W    = (const float*)d_in[18];
    const float* o_b    = (const float*)d_in[19];

    float* w       = (float*)d_ws;
    float* W2      = w;                       // 150*512    = 76800
    float* Pbz     = W2 + 76800;              // 432
    float* c_Wt    = Pbz + 432;               // 128*440    = 56320
    float* G       = c_Wt + 56320;            // 512*432    = 221184
    float* pooled2 = G + 221184;              // 16*438     = 7008
    float* partial = pooled2 + 7008;          // 128*16 + 1 counter = 2049 (pad 2080)
    float* touch   = partial + 2080;          // 64*256     = 16384
    (void)in_sizes; (void)n_in; (void)out_size; (void)ws_size;

    k_prep <<<186, 256, 0, stream>>>(emb_W, rW3, rb3, c_W, res_W,
                                     W2, Pbz, c_Wt, pooled2, partial, touch);
    k_chain<<<TBL, 256, 0, stream>>>(rW0, rb0, rW1, rb1, rW2, rb2, W2, Pbz, G);
    k_red  <<<cB * cN, 256, 0, stream>>>(xyz, Z, body23, G, res_W, res_b, pooled2);
    k_headm<<<HD, 64, 0, stream>>>(pooled2, c_Wt, c_b, bn_g, bn_b, o_W, o_b,
                                   partial, (float*)d_out);
}

// Round 30
// 59.433 us; speedup vs baseline: 1.7825x; 1.0005x over previous
//
#include <hip/hip_runtime.h>
#include <math.h>

constexpr int cB  = 16;
constexpr int cN  = 64;
constexpr int EMB = 32;
constexpr int NL  = 3;
constexpr int CDIM = 24;
constexpr int LOD = NL * CDIM;      // 72
constexpr int NB  = 10;
constexpr int H   = 150;
constexpr int CR  = 219;
constexpr int C2  = 438;
constexpr int HD  = 128;
constexpr int NSP = 6;              // species count
constexpr int GC  = NSP * LOD;      // 432 G-columns
constexpr int GCP = 512;            // padded W2 row
constexpr int TBL = 512;            // r-table resolution (measured absmax 0.0)
constexpr float RADIUS = 2.0f;

__device__ __forceinline__ float sp5(float x) {
    return fmaxf(x, 0.0f) + 0.2f * log1pf(expf(-5.0f * fabsf(x)));
}
__device__ __forceinline__ float sp1(float x) {
    return fmaxf(x, 0.0f) + log1pf(expf(-fabsf(x)));
}

// Merged prologue kernel.
// blocks 0..89: W2 build + Pbz; blocks 90..153: warm-touch res_W+rW0/1/2+xyz/Z/body23;
// blocks 154..185: c_Wt transpose (warms c_W) + zero pooled2/partial/counter.
__global__ void __launch_bounds__(256) k_prep(const float* __restrict__ emb_W,
                                              const float* __restrict__ rW3,
                                              const float* __restrict__ rb3,
                                              const float* __restrict__ c_W,
                                              const float* __restrict__ res_W,
                                              const float* __restrict__ rW0,
                                              const float* __restrict__ rW1,
                                              const float* __restrict__ rW2,
                                              const float* __restrict__ xyz,
                                              const int*   __restrict__ Zarr,
                                              const float* __restrict__ body23,
                                              float* __restrict__ W2,
                                              float* __restrict__ Pbz,
                                              float* __restrict__ c_Wt,
                                              float* __restrict__ pooled2,
                                              float* __restrict__ partial,
                                              float* __restrict__ touch) {
    int bx = blockIdx.x;
    int t = threadIdx.x;
    __shared__ float e[EMB];
    if (bx < 90) {
        int z = bx / 15, hb = bx - (bx / 15) * 15;   // 6 x 15, 10 k-rows each
        if (t < EMB) e[t] = emb_W[z * EMB + t];
        __syncthreads();
        for (int o = t; o < 10 * LOD; o += 256) {
            int k = hb * 10 + o / LOD, lo = o % LOD;
            const float* wr = &rW3[(size_t)k * (LOD * EMB) + lo * EMB];
            float s = 0.0f;
            #pragma unroll
            for (int i = 0; i < EMB; ++i) s = fmaf(wr[i], e[i], s);
            W2[(size_t)k * GCP + z * LOD + lo] = s;
        }
        if (z == 0) {  // zero the pad cols 432..511
            for (int o = t; o < 10 * (GCP - GC); o += 256) {
                int k = hb * 10 + o / (GCP - GC), c = GC + o % (GCP - GC);
                W2[(size_t)k * GCP + c] = 0.0f;
            }
        }
        if (hb == 0 && t < LOD) {
            float s = 0.0f;
            #pragma unroll
            for (int i = 0; i < EMB; ++i) s = fmaf(rb3[t * EMB + i], e[i], s);
            Pbz[z * LOD + t] = s;
        }
    } else if (bx < 154) {
        // warm-touch cold inputs for downstream kernels: res_W, rW1, rW2, rW0,
        // xyz, Z, body23. float4-coalesced; live dummy write.
        int wb = bx - 90;
        const int n_res = (CR * CR) / 4;             // 11990
        const int n_w1  = (H * H) / 4;               // 5625
        const int n_w0  = (NB * H) / 4;              // 375
        const int n_xyz = (cB * cN * 3) / 4;         // 768
        const int n_z   = (cB * cN) / 4;             // 256
        const int total = n_res + 2 * n_w1 + n_w0 + 2 * n_xyz + n_z;  // 25407
        float s = 0.0f;
        for (int i = wb * 256 + t; i < total; i += 64 * 256) {
            float4 v;
            if (i < n_res)                      v = *(const float4*)&res_W[4 * i];
            else if (i < n_res + n_w1)          v = *(const float4*)&rW1[4 * (i - n_res)];
            else if (i < n_res + 2 * n_w1)      v = *(const float4*)&rW2[4 * (i - n_res - n_w1)];
            else if (i < n_res + 2 * n_w1 + n_w0)
                v = *(const float4*)&rW0[4 * (i - n_res - 2 * n_w1)];
            else if (i < n_res + 2 * n_w1 + n_w0 + n_xyz)
                v = *(const float4*)&xyz[4 * (i - n_res - 2 * n_w1 - n_w0)];
            else if (i < n_res + 2 * n_w1 + n_w0 + 2 * n_xyz)
                v = *(const float4*)&body23[4 * (i - n_res - 2 * n_w1 - n_w0 - n_xyz)];
            else {
                const int4 zi = *(const int4*)&Zarr[4 * (i - n_res - 2 * n_w1 - n_w0 - 2 * n_xyz)];
                v.x = (float)zi.x; v.y = (float)zi.y; v.z = (float)zi.z; v.w = (float)zi.w;
            }
            s += v.x + v.y + v.z + v.w;
        }
        touch[wb * 256 + t] = s;                     // deterministic, keeps loads live
    } else {
        // misc: c_Wt transpose (HD*440) + pooled2 (cB*C2) + partial (HD*16+1 counter)
        int pb = bx - 154;                           // 32 blocks
        int totalT = HD * 440;                       // 56320
        int total2 = totalT + cB * C2 + HD * 16 + 1; // +7008+2049 = 65377
        for (int i = pb * 256 + t; i < total2; i += 32 * 256) {
            if (i < totalT) {
                int jj = i / 440, ch = i - jj * 440;
                c_Wt[i] = (ch < C2) ? c_W[ch * HD + jj] : 0.0f;
            } else if (i < totalT + cB * C2) {
                pooled2[i - totalT] = 0.0f;
            } else {
                partial[i - totalT - cB * C2] = 0.0f;  // partials + counter
            }
        }
    }
}

// Fused table chain: 1 row/block x 512 blocks (2/CU), weights streamed from L1/L2.
__global__ void __launch_bounds__(256) k_chain(const float* __restrict__ rW0,
                                               const float* __restrict__ rb0,
                                               const float* __restrict__ rW1,
                                               const float* __restrict__ rb1,
                                               const float* __restrict__ rW2,
                                               const float* __restrict__ rb2,
                                               const float* __restrict__ W2,
                                               const float* __restrict__ Pbz,
                                               float* __restrict__ G) {
    const int row = blockIdx.x;
    const int t = threadIdx.x;

    __shared__ __align__(16) float bas[10];
    __shared__ __align__(16) float hA[152];
    __shared__ __align__(16) float hB[152];

    if (t == 0) {
        float r = (float)row * (RADIUS / (float)(TBL - 1));
        #pragma unroll
        for (int k = 0; k < NB; ++k) {
            float d = r * 4.5f - (float)k;
            float v = 0.0f;
            if (fabsf(d) < 1.0f) { float cc = cosf(1.57079632679489662f * d); v = cc * cc; }
            bas[k] = v;
        }
    }
    __syncthreads();

    // ---- L0: K=10 ----
    if (t < H) {
        float a0 = 0;
        #pragma unroll
        for (int k = 0; k < NB; ++k)
            a0 = fmaf(bas[k], rW0[k * H + t], a0);
        hA[t] = sp5(a0 + rb0[t]);
    }
    __syncthreads();

    // ---- L1 (hA->hB), L2 (hB->hA): K=150 ----
    for (int layer = 0; layer < 2; ++layer) {
        const float* W   = layer ? rW2 : rW1;
        const float* bb  = layer ? rb2 : rb1;
        const float* src = layer ? hB : hA;
        float*       dst = layer ? hA : hB;
        float a0 = 0;
        if (t < H) {
            #pragma unroll 10
            for (int k = 0; k < H; ++k)
                a0 = fmaf(src[k], W[k * H + t], a0);
        }
        __syncthreads();
        if (t < H) dst[t] = sp5(a0 + bb[t]);
        __syncthreads();
    }

    // ---- G: out[row][c] = sum_k hA[k]*W2[k][c] + Pbz[c], c = 4t..4t+4 ----
    if (t < 108) {
        const int g0 = 4 * t;
        float4 c0 = {0, 0, 0, 0};
        #pragma unroll 10
        for (int k = 0; k < H; ++k) {
            float x = hA[k];
            float4 w = *(const float4*)&W2[(size_t)k * GCP + g0];
            c0.x = fmaf(x, w.x, c0.x); c0.y = fmaf(x, w.y, c0.y);
            c0.z = fmaf(x, w.z, c0.z); c0.w = fmaf(x, w.w, c0.w);
        }
        float4 p = *(const float4*)&Pbz[g0];
        float4 o;
        o.x = c0.x + p.x; o.y = c0.y + p.y; o.z = c0.z + p.z; o.w = c0.w + p.w;
        *(float4*)&G[(size_t)row * GC + g0] = o;
    }
}

// Fully fused per (b,a): ballot-compacted gather + Y-reduce -> xr; in-block residual
// GEMM vs L2-warm res_W; xv^2 and o^2 atomically accumulated into pooled2.
__global__ void __launch_bounds__(256) k_red(const float* __restrict__ xyz,
                                             const int* __restrict__ Z,
                                             const float* __restrict__ body23,
                                             const float* __restrict__ G,
                                             const float* __restrict__ res_W,
                                             const float* __restrict__ res_b,
                                             float* __restrict__ pooled2) {
    int ba = blockIdx.x;
    int b = ba >> 6, a = ba & 63;
    int t = threadIdx.x;
    __shared__ float ym[64][12];
    __shared__ float ymc[64][12];
    __shared__ __align__(16) float ps[64][76];
    __shared__ float xr[224];
    __shared__ int t0s[64];
    __shared__ float wls[64];
    __shared__ int zs[64];
    __shared__ int alist[64];
    __shared__ int cnt_s;
    if (t < 64) {
        int n = t;
        float ax = xyz[((size_t)b * cN + a) * 3 + 0];
        float ay = xyz[((size_t)b * cN + a) * 3 + 1];
        float az = xyz[((size_t)b * cN + a) * 3 + 2];
        float d0 = ax - xyz[((size_t)b * cN + n) * 3 + 0];
        float d1 = ay - xyz[((size_t)b * cN + n) * 3 + 1];
        float d2 = az - xyz[((size_t)b * cN + n) * 3 + 2];
        float s = d0 * d0 + d1 * d1 + d2 * d2;
        float r = sqrtf(s + 1e-12f);
        bool m = (r < RADIUS) && (r > 1e-6f);
        float u = r * ((float)(TBL - 1) / RADIUS);
        int t0 = (int)u;
        if (t0 > TBL - 2) t0 = TBL - 2;
        t0s[n] = t0;
        wls[n] = u - (float)t0;
        zs[n] = Z[b * cN + n];
        float inv = 1.0f / r;
        float x = d0 * inv, y = d1 * inv, z = d2 * inv;
        ym[n][0] = 0.28209479177387814f;
        ym[n][1] = 0.4886025119029199f * y;
        ym[n][2] = 0.4886025119029199f * z;
        ym[n][3] = 0.4886025119029199f * x;
        ym[n][4] = 1.0925484305920792f * x * y;
        ym[n][5] = 1.0925484305920792f * y * z;
        ym[n][6] = 0.31539156525252005f * (3.0f * z * z - 1.0f);
        ym[n][7] = 1.0925484305920792f * x * z;
        ym[n][8] = 0.5462742152960396f * (x * x - y * y);
        // ballot compaction (wave 0 only; t==lane)
        unsigned long long mask = __ballot(m);
        int rank = __popcll(mask & ((1ull << n) - 1ull));
        if (m) alist[rank] = n;
        if (n == 0) cnt_s = (int)__popcll(mask);
    }
    __syncthreads();
    int cnt = cnt_s;
    // compact ym rows
    for (int i = t; i < cnt * 9; i += 256) {
        int ci = i / 9, yi = i - ci * 9;
        ymc[ci][yi] = ym[alist[ci]][yi];
    }
    // compacted float4 gather+lerp: 18 float4 groups per active neighbor
    for (int i = t; i < cnt * 18; i += 256) {
        int ci = i / 18, q = i - ci * 18;
        int n = alist[ci];
        const float* g = &G[(size_t)t0s[n] * GC + zs[n] * LOD + 4 * q];
        float4 g0 = *(const float4*)g;
        float4 g1 = *(const float4*)(g + GC);
        float wl = wls[n];
        float4 v;
        v.x = g0.x + wl * (g1.x - g0.x);
        v.y = g0.y + wl * (g1.y - g0.y);
        v.z = g0.z + wl * (g1.z - g0.z);
        v.w = g0.w + wl * (g1.w - g0.w);
        *(float4*)&ps[ci][4 * q] = v;
    }
    __syncthreads();
    if (t < 216) {
        int lo, yi;
        if (t < 24) { lo = t; yi = 0; }
        else if (t < 96) { int q = t - 24; int o = q / 3; lo = 24 + o; yi = 1 + (q - o * 3); }
        else { int q = t - 96; int o = q / 5; lo = 48 + o; yi = 4 + (q - o * 5); }
        float acc = 0.0f;
        #pragma unroll 4
        for (int ci = 0; ci < cnt; ++ci)
            acc = fmaf(ps[ci][lo], ymc[ci][yi], acc);
        xr[3 + t] = acc * 0.125f;
    } else if (t < 219) {
        xr[t - 216] = body23[(size_t)ba * 3 + (t - 216)];
    }
    __syncthreads();
    // in-block residual: s[t] = sum_k xr[k] * res_W[k][t]  (coalesced, L2-warm)
    if (t < CR) {
        float xv = xr[t];
        float s = 0.0f;
        #pragma unroll 8
        for (int k = 0; k < CR; ++k)
            s = fmaf(xr[k], res_W[(size_t)k * CR + t], s);
        float o = xv + sp5(res_b[t] + s);
        atomicAdd(&pooled2[b * C2 + t],      xv * xv);
        atomicAdd(&pooled2[b * C2 + CR + t], o * o);
    }
}

// Merged head, contention-free: block j computes hh[b][j], BN over b, softplus,
// writes its own partial row partial[j][16]; last block reduces 128x16 + sigmoid.
__global__ void __launch_bounds__(64) k_headm(const float* __restrict__ pooled2,
                                              const float* __restrict__ c_Wt,
                                              const float* __restrict__ c_b,
                                              const float* __restrict__ bn_g,
                                              const float* __restrict__ bn_b,
                                              const float* __restrict__ o_W,
                                              const float* __restrict__ o_b,
                                              float* __restrict__ partial,
                                              float* __restrict__ out) {
    int j = blockIdx.x;
    int l = threadIdx.x;
    float acc[cB];
    #pragma unroll
    for (int b = 0; b < cB; ++b) acc[b] = 0.0f;
    const float* wr = &c_Wt[j * 440];
    for (int ch = l; ch < C2; ch += 64) {
        float wv = wr[ch];
        #pragma unroll
        for (int b = 0; b < cB; ++b)
            acc[b] = fmaf(sqrtf(pooled2[b * C2 + ch]), wv, acc[b]);
    }
    #pragma unroll
    for (int off = 32; off >= 1; off >>= 1) {
        #pragma unroll
        for (int b = 0; b < cB; ++b) acc[b] += __shfl_xor(acc[b], off, 64);
    }
    __shared__ int is_last;
    if (l == 0) {
        float cb = c_b[j];
        float h[cB];
        float mu = 0.0f;
        #pragma unroll
        for (int b = 0; b < cB; ++b) { h[b] = sp1(acc[b] + cb); mu += h[b]; }
        mu *= (1.0f / cB);
        float var = 0.0f;
        #pragma unroll
        for (int b = 0; b < cB; ++b) { float d = h[b] - mu; var = fmaf(d, d, var); }
        var *= (1.0f / cB);
        float sc = bn_g[j] / sqrtf(var + 1e-5f);
        float bnb = bn_b[j];
        float ow = o_W[j];
        #pragma unroll
        for (int b = 0; b < cB; ++b)
            partial[j * cB + b] = sp1((h[b] - mu) * sc + bnb) * ow;   // own row, no atomics
        __threadfence();
        unsigned int old = atomicAdd((unsigned int*)&partial[HD * cB], 1u);
        is_last = (old == (unsigned int)(HD - 1));
    }
    __syncthreads();
    if (is_last) {
        // reduce partial[128][16]: lane l sums 32 rows for column (l&15), group l>>4
        int bcol = l & 15, grp = l >> 4;
        float s = 0.0f;
        #pragma unroll 8
        for (int jr = grp * 32; jr < grp * 32 + 32; ++jr)
            s += partial[jr * cB + bcol];
        s += __shfl_down(s, 32, 64);
        s += __shfl_down(s, 16, 64);
        if (l < cB)
            out[l] = 1.0f / (1.0f + expf(-(s + o_b[0])));
    }
}

extern "C" void kernel_launch(void* const* d_in, const int* in_sizes, int n_in,
                              void* d_out, int out_size, void* d_ws, size_t ws_size,
                              hipStream_t stream) {
    const float* xyz    = (const float*)d_in[0];
    const int*   Z      = (const int*)d_in[1];
    const float* body23 = (const float*)d_in[2];
    const float* emb_W  = (const float*)d_in[3];
    const float* rW0    = (const float*)d_in[4];
    const float* rb0    = (const float*)d_in[5];
    const float* rW1    = (const float*)d_in[6];
    const float* rb1    = (const float*)d_in[7];
    const float* rW2    = (const float*)d_in[8];
    const float* rb2    = (const float*)d_in[9];
    const float* rW3    = (const float*)d_in[10];
    const float* rb3    = (const float*)d_in[11];
    const float* res_W  = (const float*)d_in[12];
    const float* res_b  = (const float*)d_in[13];
    const float* c_W    = (const float*)d_in[14];
    const float* c_b    = (const float*)d_in[15];
    const float* bn_g   = (const float*)d_in[16];
    const float* bn_b   = (const float*)d_in[17];
    const float* o_W    = (const float*)d_in[18];
    const float* o_b    = (const float*)d_in[19];

    float* w       = (float*)d_ws;
    float* W2      = w;                       // 150*512    = 76800
    float* Pbz     = W2 + 76800;              // 432
    float* c_Wt    = Pbz + 432;               // 128*440    = 56320
    float* G       = c_Wt + 56320;            // 512*432    = 221184
    float* pooled2 = G + 221184;              // 16*438     = 7008
    float* partial = pooled2 + 7008;          // 128*16 + 1 counter = 2049 (pad 2080)
    float* touch   = partial + 2080;          // 64*256     = 16384
    (void)in_sizes; (void)n_in; (void)out_size; (void)ws_size;

    k_prep <<<186, 256, 0, stream>>>(emb_W, rW3, rb3, c_W, res_W,
                                     rW0, rW1, rW2, xyz, Z, body23,
                                     W2, Pbz, c_Wt, pooled2, partial, touch);
    k_chain<<<TBL, 256, 0, stream>>>(rW0, rb0, rW1, rb1, rW2, rb2, W2, Pbz, G);
    k_red  <<<cB * cN, 256, 0, stream>>>(xyz, Z, body23, G, res_W, res_b, pooled2);
    k_headm<<<HD, 64, 0, stream>>>(pooled2, c_Wt, c_b, bn_g, bn_b, o_W, o_b,
                                   partial, (float*)d_out);
}